// Round 3
// baseline (923.221 us; speedup 1.0000x reference)
//
#include <hip/hip_runtime.h>
#include <cstdint>
#include <cstddef>

// Problem constants
#define Bb   256
#define Tt   512
#define Ii   300
#define Hh   128
#define G4   512      // 4*H
#define KP   320      // K padded to multiple of 32 for MFMA
#define Mm   (Bb*Tt)  // 131072 rows of phase-1 GEMM

typedef _Float16 h2v   __attribute__((ext_vector_type(2)));
typedef _Float16 half8 __attribute__((ext_vector_type(8)));
typedef float    f32x4 __attribute__((ext_vector_type(4)));

static __device__ __forceinline__ h2v as_h2(unsigned int u){ union{unsigned int u; h2v h;} c; c.u=u; return c.h; }
static __device__ __forceinline__ unsigned int as_u32(h2v h){ union{unsigned int u; h2v h;} c; c.h=h; return c.u; }

#if __has_builtin(__builtin_amdgcn_fdot2)
#define FDOT2(a,b,c) __builtin_amdgcn_fdot2((a),(b),(c),false)
#else
static __device__ __forceinline__ float FDOT2(h2v a, h2v b, float c){
  return c + (float)a[0]*(float)b[0] + (float)a[1]*(float)b[1];
}
#endif

// quad_perm DPP: permute within each 4-lane group, 1 VALU instr.
template<int CTRL>
static __device__ __forceinline__ float qperm(float v){
  union{float f; int i;} c; c.f = v;
  c.i = __builtin_amdgcn_update_dpp(c.i, c.i, CTRL, 0xF, 0xF, false);
  return c.f;
}
#define QP_XOR1 0xB1   // [1,0,3,2]
#define QP_XOR2 0x4E   // [2,3,0,1]
#define QP_XOR3 0x1B   // [3,2,1,0]

// ---------------- conversion: x fp32 [131072,300] -> f16 padded [131072,320] ----------------
__global__ __launch_bounds__(256) void conv_x(const float* __restrict__ x, unsigned int* __restrict__ x16){
  int idx = blockIdx.x*256 + threadIdx.x;      // half2 index; total 131072*160, grid exact
  int r   = idx / 160;
  int kk2 = idx - r*160;
  int kk  = kk2*2;
  const float* xr = x + (size_t)r*Ii;
  float v0 = (kk   < Ii) ? xr[kk]   : 0.f;
  float v1 = (kk+1 < Ii) ? xr[kk+1] : 0.f;
  h2v h; h[0] = (_Float16)v0; h[1] = (_Float16)v1;
  x16[idx] = as_u32(h);
}

// ---------------- conversion: W_ih -> f16 padded (rows PERMUTED pr=d*4+g), Whh packed, bias sum ---
// Row permutation: output row pr corresponds to original gate row gc = (pr&3)*128 + (pr>>2).
__global__ __launch_bounds__(256) void conv_small(const float* __restrict__ Wih, const float* __restrict__ Whh,
      const float* __restrict__ bih, const float* __restrict__ bhh,
      unsigned int* __restrict__ W16, unsigned int* __restrict__ Whh2, float* __restrict__ bias){
  int idx = blockIdx.x*256 + threadIdx.x;
  if (idx < G4*160){
    int pr = idx/160, kk2 = idx - pr*160, kk = kk2*2;
    int gc = (pr&3)*128 + (pr>>2);
    const float* wr = Wih + (size_t)gc*Ii;
    float v0 = (kk   < Ii) ? wr[kk]   : 0.f;
    float v1 = (kk+1 < Ii) ? wr[kk+1] : 0.f;
    h2v h; h[0]=(_Float16)v0; h[1]=(_Float16)v1;
    W16[idx] = as_u32(h);
  } else if (idx < G4*160 + G4*64){
    int t = idx - G4*160; int pr = t>>6, kk = t&63;
    int gc = (pr&3)*128 + (pr>>2);
    float v0 = Whh[gc*Hh + kk*2], v1 = Whh[gc*Hh + kk*2 + 1];
    h2v h; h[0]=(_Float16)v0; h[1]=(_Float16)v1;
    Whh2[t] = as_u32(h);
  } else if (idx < G4*160 + G4*64 + G4){
    int pr = idx - (G4*160 + G4*64);
    int gc = (pr&3)*128 + (pr>>2);
    bias[pr] = bih[gc] + bhh[gc];
  }
}

// ---------------- phase 1: xg[131072,512] = A16 @ W16^T + bias, f16 MFMA (unchanged) ----------------
__global__ __launch_bounds__(256,2) void gemm16(const _Float16* __restrict__ A, const _Float16* __restrict__ Bm,
       const float* __restrict__ bias, float* __restrict__ C){
  __shared__ _Float16 As[128][32];
  __shared__ _Float16 Bs[128][32];
  int tid = threadIdx.x;
  int w = tid>>6, lane = tid&63;
  int bm = blockIdx.x*128, bn = blockIdx.y*128;
  f32x4 acc[2][8];
  #pragma unroll
  for (int i=0;i<2;i++)
    #pragma unroll
    for (int j=0;j<8;j++) acc[i][j] = (f32x4){0.f,0.f,0.f,0.f};

  int srow = tid>>1, scol = (tid&1)*16;
  const uint4* ga = (const uint4*)(A  + (size_t)(bm+srow)*KP + scol);
  const uint4* gb = (const uint4*)(Bm + (size_t)(bn+srow)*KP + scol);

  int q = lane>>4, mr = lane&15;
  int m0 = w*32;

  for (int kt=0; kt<KP/32; ++kt){
    __syncthreads();
    uint4 va0 = ga[0], va1 = ga[1];
    uint4 vb0 = gb[0], vb1 = gb[1];
    *(uint4*)&As[srow][scol]   = va0; *(uint4*)&As[srow][scol+8] = va1;
    *(uint4*)&Bs[srow][scol]   = vb0; *(uint4*)&Bs[srow][scol+8] = vb1;
    ga += 4; gb += 4;  // advance 32 halves within the row
    __syncthreads();
    half8 af0 = *(const half8*)&As[m0 + mr][q*8];
    half8 af1 = *(const half8*)&As[m0 + 16 + mr][q*8];
    #pragma unroll
    for (int j=0;j<8;j++){
      half8 bf = *(const half8*)&Bs[j*16 + mr][q*8];
      acc[0][j] = __builtin_amdgcn_mfma_f32_16x16x32_f16(af0, bf, acc[0][j], 0,0,0);
      acc[1][j] = __builtin_amdgcn_mfma_f32_16x16x32_f16(af1, bf, acc[1][j], 0,0,0);
    }
  }
  // epilogue: C/D layout col=lane&15, row=(lane>>4)*4+reg
  #pragma unroll
  for (int j=0;j<8;j++){
    int gc = bn + j*16 + mr;
    float bv = bias[gc];
    #pragma unroll
    for (int i=0;i<2;i++){
      int gr0 = bm + w*32 + i*16 + q*4;
      #pragma unroll
      for (int reg=0; reg<4; ++reg)
        C[(size_t)(gr0+reg)*G4 + gc] = acc[i][j][reg] + bv;
    }
  }
}

// ---------------- phase 2: recurrence, TWO batch rows per block ----------------
// 512 threads, tid = d*4 + g. Each thread holds ONE gate-row's weights (64 half2
// regs, loaded once) and computes that gate for TWO batches per step — the fixed
// per-step latency (barrier, LDS broadcast drain, exp chains, prefetch waits) is
// amortized over 2 batches, filling the ~36% idle issue slots seen in rocprof.
// Gate exchange = quad_perm DPP (pure VALU). One barrier per step via
// double-buffered hsh. xg prefetched 2 steps deep to cover ~900-cyc HBM latency.
__global__ __launch_bounds__(512,1) void lstm_rec(const float* __restrict__ xg, const unsigned int* __restrict__ Whh2,
     const float* __restrict__ fcw, const float* __restrict__ fcb, float* __restrict__ out){
  int tid = threadIdx.x;           // 0..511
  int b2 = blockIdx.x;             // handles batches 2*b2, 2*b2+1
  int d = tid >> 2, g = tid & 3;
  h2v w[64];
  #pragma unroll
  for (int kk=0; kk<64; ++kk) w[kk] = as_h2(Whh2[tid*64 + kk]);

  __shared__ __align__(16) unsigned short hsh[2][2][128];  // [buf][batch][d]
  __shared__ float red[256];
  if (tid < 256) ((unsigned short*)hsh)[tid] = 0;          // zero hsh[0][*][*]
  float c0 = 0.f, h0 = 0.f, c1 = 0.f, h1 = 0.f;
  const float* xrow0 = xg + (size_t)(2*b2)   * (Tt*G4);
  const float* xrow1 = xg + (size_t)(2*b2+1) * (Tt*G4);
  // 2-deep prefetch pipeline
  float xc0 = xrow0[tid],        xc1 = xrow1[tid];
  float xa0 = xrow0[G4 + tid],   xa1 = xrow1[G4 + tid];
  int b0m = g & 1;
  int b1m = (g >> 1) & 1;
  float km = (g == 2) ? 2.f : 1.f;   // tanh(a) = 2*sigmoid(2a)-1
  __syncthreads();

  for (int t=0; t<Tt; ++t){
    // issue next-next-step loads first (tail clamped to last row; clamped value
    // is provably never consumed)
    int tl = (t+2 < Tt) ? (t+2) : (Tt-1);
    float xb0 = xrow0[(size_t)tl*G4 + tid];
    float xb1 = xrow1[(size_t)tl*G4 + tid];

    const uint4* hv0 = (const uint4*)hsh[t & 1][0];
    const uint4* hv1 = (const uint4*)hsh[t & 1][1];
    float p0 = xc0, p1 = 0.f, p2 = 0.f, p3 = 0.f;
    float q0 = xc1, q1 = 0.f, q2 = 0.f, q3 = 0.f;
    #pragma unroll
    for (int kq=0; kq<8; ++kq){
      uint4 ha = hv0[kq*2], hb = hv0[kq*2+1];
      uint4 hc = hv1[kq*2], hd = hv1[kq*2+1];
      p0 = FDOT2(as_h2(ha.x), w[kq*8+0], p0);
      p1 = FDOT2(as_h2(ha.y), w[kq*8+1], p1);
      p2 = FDOT2(as_h2(ha.z), w[kq*8+2], p2);
      p3 = FDOT2(as_h2(ha.w), w[kq*8+3], p3);
      q0 = FDOT2(as_h2(hc.x), w[kq*8+0], q0);
      q1 = FDOT2(as_h2(hc.y), w[kq*8+1], q1);
      q2 = FDOT2(as_h2(hc.z), w[kq*8+2], q2);
      q3 = FDOT2(as_h2(hc.w), w[kq*8+3], q3);
      p0 = FDOT2(as_h2(hb.x), w[kq*8+4], p0);
      p1 = FDOT2(as_h2(hb.y), w[kq*8+5], p1);
      p2 = FDOT2(as_h2(hb.z), w[kq*8+6], p2);
      p3 = FDOT2(as_h2(hb.w), w[kq*8+7], p3);
      q0 = FDOT2(as_h2(hd.x), w[kq*8+4], q0);
      q1 = FDOT2(as_h2(hd.y), w[kq*8+5], q1);
      q2 = FDOT2(as_h2(hd.z), w[kq*8+6], q2);
      q3 = FDOT2(as_h2(hd.w), w[kq*8+7], q3);
    }
    float aA = (p0 + p1) + (p2 + p3);
    float aB = (q0 + q1) + (q2 + q3);
    // activations for both batches (independent chains -> ILP on the trans unit)
    float sA  = 1.f/(1.f + __expf(-km*aA));
    float sB  = 1.f/(1.f + __expf(-km*aB));
    float actA = (g == 2) ? (2.f*sA - 1.f) : sA;
    float actB = (g == 2) ? (2.f*sB - 1.f) : sB;
    // intra-quad all-to-all via DPP quad_perm
    float uA1 = qperm<QP_XOR1>(actA), uA2 = qperm<QP_XOR2>(actA), uA3 = qperm<QP_XOR3>(actA);
    float uB1 = qperm<QP_XOR1>(actB), uB2 = qperm<QP_XOR2>(actB), uB3 = qperm<QP_XOR3>(actB);
    {
      float pl = b0m ? uA1  : actA, ph = b0m ? uA3 : uA2;
      float ql = b0m ? actA : uA1,  qh = b0m ? uA2 : uA3;
      float i_ = b1m ? ph : pl, f_ = b1m ? qh : ql;
      float g_ = b1m ? pl : ph, o_ = b1m ? ql : qh;
      c0 = f_*c0 + i_*g_;
      float ec = __expf(2.f*c0); float tc = 1.f - 2.f/(ec+1.f);
      h0 = o_*tc;
    }
    {
      float pl = b0m ? uB1  : actB, ph = b0m ? uB3 : uB2;
      float ql = b0m ? actB : uB1,  qh = b0m ? uB2 : uB3;
      float i_ = b1m ? ph : pl, f_ = b1m ? qh : ql;
      float g_ = b1m ? pl : ph, o_ = b1m ? ql : qh;
      c1 = f_*c1 + i_*g_;
      float ec = __expf(2.f*c1); float tc = 1.f - 2.f/(ec+1.f);
      h1 = o_*tc;
    }
    if (g == 0){
      union{ _Float16 f; unsigned short s; } cv; cv.f = (_Float16)h0;
      hsh[(t+1) & 1][0][d] = cv.s;
    } else if (g == 1){
      union{ _Float16 f; unsigned short s; } cv; cv.f = (_Float16)h1;
      hsh[(t+1) & 1][1][d] = cv.s;
    }
    __syncthreads();
    xc0 = xa0; xa0 = xb0;
    xc1 = xa1; xa1 = xb1;
  }

  // fused FC for both batches: out[2b2+bi] = sum_d h_d * fcw[d] + fcb
  if (g == 0) red[d]       = h0 * fcw[d];
  else if (g == 1) red[128 + d] = h1 * fcw[d];
  __syncthreads();
  #pragma unroll
  for (int s2=64; s2>=1; s2>>=1){
    if ((tid & 127) < s2 && tid < 256) red[tid] += red[tid+s2];
    __syncthreads();
  }
  if (tid == 0)   out[2*b2]   = red[0]   + fcb[0];
  if (tid == 128) out[2*b2+1] = red[128] + fcb[0];
}

extern "C" void kernel_launch(void* const* d_in, const int* in_sizes, int n_in,
                              void* d_out, int out_size, void* d_ws, size_t ws_size,
                              hipStream_t stream){
  const float* x   = (const float*)d_in[0];
  const float* Wih = (const float*)d_in[1];
  const float* Whh = (const float*)d_in[2];
  const float* bih = (const float*)d_in[3];
  const float* bhh = (const float*)d_in[4];
  const float* fcw = (const float*)d_in[5];
  const float* fcb = (const float*)d_in[6];
  float* out = (float*)d_out;
  char* ws = (char*)d_ws;

  // ws layout (bytes):
  //   x16  : 0          .. 83,886,080   (131072*320 f16)
  //   W16  : 83,886,080 .. +327,680     (512*320 f16, rows permuted d*4+g)
  //   Whh2 : 84,213,760 .. +131,072     (512*64 half2, rows permuted d*4+g)
  //   bias : 84,344,832 .. +2,048       (512 f32, permuted d*4+g)
  //   xg   : 84,346,880 .. +268,435,456 (131072*512 f32, cols permuted d*4+g)
  unsigned int* x16   = (unsigned int*)(ws);
  unsigned int* W16   = (unsigned int*)(ws + 83886080);
  unsigned int* Whh2w = (unsigned int*)(ws + 84213760);
  float*        bias  = (float*)      (ws + 84344832);
  float*        xg    = (float*)      (ws + 84346880);

  hipLaunchKernelGGL(conv_x,     dim3(81920),  dim3(256), 0, stream, x, x16);
  hipLaunchKernelGGL(conv_small, dim3(450),    dim3(256), 0, stream, Wih, Whh, bih, bhh, W16, Whh2w, bias);
  hipLaunchKernelGGL(gemm16,     dim3(1024,4), dim3(256), 0, stream,
                     (const _Float16*)x16, (const _Float16*)W16, bias, xg);
  hipLaunchKernelGGL(lstm_rec,   dim3(128),    dim3(512), 0, stream, xg, Whh2w, fcw, fcb, out);
}

// Round 5
// 765.327 us; speedup vs baseline: 1.2063x; 1.2063x over previous
//
#include <hip/hip_runtime.h>
#include <cstdint>
#include <cstddef>

// Problem constants
#define Bb   256
#define Tt   512
#define Ii   300
#define Hh   128
#define G4   512      // 4*H
#define KP   320      // K padded to multiple of 32 for MFMA
#define Mm   (Bb*Tt)  // 131072 rows of phase-1 GEMM

typedef _Float16 h2v   __attribute__((ext_vector_type(2)));
typedef _Float16 half8 __attribute__((ext_vector_type(8)));
typedef float    f32x4 __attribute__((ext_vector_type(4)));

static __device__ __forceinline__ h2v as_h2(unsigned int u){ union{unsigned int u; h2v h;} c; c.u=u; return c.h; }
static __device__ __forceinline__ unsigned int as_u32(h2v h){ union{unsigned int u; h2v h;} c; c.h=h; return c.u; }

#if __has_builtin(__builtin_amdgcn_fdot2)
#define FDOT2(a,b,c) __builtin_amdgcn_fdot2((a),(b),(c),false)
#else
static __device__ __forceinline__ float FDOT2(h2v a, h2v b, float c){
  return c + (float)a[0]*(float)b[0] + (float)a[1]*(float)b[1];
}
#endif

// DPP lane permutes (pure VALU, 1 instr each)
template<int CTRL>
static __device__ __forceinline__ float qperm(float v){
  union{float f; int i;} c; c.f = v;
  c.i = __builtin_amdgcn_update_dpp(c.i, c.i, CTRL, 0xF, 0xF, false);
  return c.f;
}
#define QP_XOR1   0xB1   // quad_perm [1,0,3,2]  : lane^1
#define QP_XOR2   0x4E   // quad_perm [2,3,0,1]  : lane^2
#define QP_XOR3   0x1B   // quad_perm [3,2,1,0]  : lane^3
#define ROW_HMIRR 0x141  // row_half_mirror      : lane^7 (within 8-lane halves)

// ---------------- conversion: x fp32 [131072,300] -> f16 padded [131072,320] ----------------
__global__ __launch_bounds__(256) void conv_x(const float* __restrict__ x, unsigned int* __restrict__ x16){
  int idx = blockIdx.x*256 + threadIdx.x;      // half2 index; total 131072*160, grid exact
  int r   = idx / 160;
  int kk2 = idx - r*160;
  int kk  = kk2*2;
  const float* xr = x + (size_t)r*Ii;
  float v0 = (kk   < Ii) ? xr[kk]   : 0.f;
  float v1 = (kk+1 < Ii) ? xr[kk+1] : 0.f;
  h2v h; h[0] = (_Float16)v0; h[1] = (_Float16)v1;
  x16[idx] = as_u32(h);
}

// ---------------- conversion: W_ih -> f16 padded (rows PERMUTED pr=d*4+g), Whh packed, bias sum ---
// W_ih row permutation: output row pr corresponds to original gate row gc = (pr&3)*128 + (pr>>2).
// Whh packed for the K-SPLIT recurrence: thread tid = pr*2+kh holds half2 j=0..31 of
// original row gc, K-half kh  ->  Whh2[tid*32 + j].
__global__ __launch_bounds__(256) void conv_small(const float* __restrict__ Wih, const float* __restrict__ Whh,
      const float* __restrict__ bih, const float* __restrict__ bhh,
      unsigned int* __restrict__ W16, unsigned int* __restrict__ Whh2, float* __restrict__ bias){
  int idx = blockIdx.x*256 + threadIdx.x;
  if (idx < G4*160){
    int pr = idx/160, kk2 = idx - pr*160, kk = kk2*2;
    int gc = (pr&3)*128 + (pr>>2);
    const float* wr = Wih + (size_t)gc*Ii;
    float v0 = (kk   < Ii) ? wr[kk]   : 0.f;
    float v1 = (kk+1 < Ii) ? wr[kk+1] : 0.f;
    h2v h; h[0]=(_Float16)v0; h[1]=(_Float16)v1;
    W16[idx] = as_u32(h);
  } else if (idx < G4*160 + 1024*32){
    int t = idx - G4*160;            // 0..32767
    int thrd = t >> 5, j = t & 31;   // owning thread, half2-slot
    int pr = thrd >> 1, kh = thrd & 1;
    int gc = (pr&3)*128 + (pr>>2);
    int kk = kh*32 + j;              // half2 index within the row (K=128 -> 64 half2)
    float v0 = Whh[gc*Hh + kk*2], v1 = Whh[gc*Hh + kk*2 + 1];
    h2v h; h[0]=(_Float16)v0; h[1]=(_Float16)v1;
    Whh2[t] = as_u32(h);
  } else if (idx < G4*160 + 1024*32 + G4){
    int pr = idx - (G4*160 + 1024*32);
    int gc = (pr&3)*128 + (pr>>2);
    bias[pr] = bih[gc] + bhh[gc];
  }
}

// ---------------- phase 1: xg[131072,512] = A16 @ W16^T + bias, f16 MFMA (unchanged) ----------------
__global__ __launch_bounds__(256,2) void gemm16(const _Float16* __restrict__ A, const _Float16* __restrict__ Bm,
       const float* __restrict__ bias, float* __restrict__ C){
  __shared__ _Float16 As[128][32];
  __shared__ _Float16 Bs[128][32];
  int tid = threadIdx.x;
  int w = tid>>6, lane = tid&63;
  int bm = blockIdx.x*128, bn = blockIdx.y*128;
  f32x4 acc[2][8];
  #pragma unroll
  for (int i=0;i<2;i++)
    #pragma unroll
    for (int j=0;j<8;j++) acc[i][j] = (f32x4){0.f,0.f,0.f,0.f};

  int srow = tid>>1, scol = (tid&1)*16;
  const uint4* ga = (const uint4*)(A  + (size_t)(bm+srow)*KP + scol);
  const uint4* gb = (const uint4*)(Bm + (size_t)(bn+srow)*KP + scol);

  int q = lane>>4, mr = lane&15;
  int m0 = w*32;

  for (int kt=0; kt<KP/32; ++kt){
    __syncthreads();
    uint4 va0 = ga[0], va1 = ga[1];
    uint4 vb0 = gb[0], vb1 = gb[1];
    *(uint4*)&As[srow][scol]   = va0; *(uint4*)&As[srow][scol+8] = va1;
    *(uint4*)&Bs[srow][scol]   = vb0; *(uint4*)&Bs[srow][scol+8] = vb1;
    ga += 4; gb += 4;  // advance 32 halves within the row
    __syncthreads();
    half8 af0 = *(const half8*)&As[m0 + mr][q*8];
    half8 af1 = *(const half8*)&As[m0 + 16 + mr][q*8];
    #pragma unroll
    for (int j=0;j<8;j++){
      half8 bf = *(const half8*)&Bs[j*16 + mr][q*8];
      acc[0][j] = __builtin_amdgcn_mfma_f32_16x16x32_f16(af0, bf, acc[0][j], 0,0,0);
      acc[1][j] = __builtin_amdgcn_mfma_f32_16x16x32_f16(af1, bf, acc[1][j], 0,0,0);
    }
  }
  // epilogue: C/D layout col=lane&15, row=(lane>>4)*4+reg
  #pragma unroll
  for (int j=0;j<8;j++){
    int gc = bn + j*16 + mr;
    float bv = bias[gc];
    #pragma unroll
    for (int i=0;i<2;i++){
      int gr0 = bm + w*32 + i*16 + q*4;
      #pragma unroll
      for (int reg=0; reg<4; ++reg)
        C[(size_t)(gr0+reg)*G4 + gc] = acc[i][j][reg] + bv;
    }
  }
}

// ---------------- phase 2: recurrence, one block per batch, K-SPLIT across 1024 threads --------
// tid = pr*2 + kh : pr = gate-row (0..511, = d*4+g), kh = K-half (0/1).
// Each thread holds 32 half2 weights and computes a HALF dot; the kh pair reduces
// with one DPP quad_perm(^1). 16 waves/block = 4 waves/SIMD (2x round-1's latency
// hiding) while per-wave work halves. Gate exchange within the 8-lane d-group is
// pure-VALU DPP: ^2 (quad), ^7 (row_half_mirror, kh-invariant), ^4 (= ^7 then ^3).
// One barrier per step via double-buffered hsh; xg prefetched 2 steps deep.
__global__ __launch_bounds__(1024) void lstm_rec(const float* __restrict__ xg, const unsigned int* __restrict__ Whh2,
     const float* __restrict__ fcw, const float* __restrict__ fcb, float* __restrict__ out){
  int tid = threadIdx.x;           // 0..1023
  int b = blockIdx.x;
  int pr = tid >> 1, kh = tid & 1;
  int g = pr & 3;
  h2v w[32];
  #pragma unroll
  for (int j=0; j<32; ++j) w[j] = as_h2(Whh2[tid*32 + j]);

  __shared__ __align__(16) unsigned short hsh[2][128];
  __shared__ float red[128];
  if (tid < 128) hsh[0][tid] = 0;
  float creg = 0.f, hreg = 0.f;
  const float* xrow = xg + (size_t)b * (Tt*G4);
  float xc = xrow[pr];
  float xa = xrow[G4 + pr];
  int b0m = g & 1;
  int b1m = (g >> 1) & 1;
  float km = (g == 2) ? 2.f : 1.f;   // tanh(a) = 2*sigmoid(2a)-1
  __syncthreads();

  for (int t=0; t<Tt; ++t){
    // next-next-step load first (tail clamped; clamped value never consumed)
    int tl = (t+2 < Tt) ? (t+2) : (Tt-1);
    float xb = xrow[(size_t)tl*G4 + pr];

    const uint4* hv = (const uint4*)hsh[t & 1] + kh*8;  // this thread's K-half (128B)
    float p0 = kh ? 0.f : xc, p1 = 0.f, p2 = 0.f, p3 = 0.f;
    #pragma unroll
    for (int kq=0; kq<4; ++kq){
      uint4 ha = hv[kq*2], hb = hv[kq*2+1];
      p0 = FDOT2(as_h2(ha.x), w[kq*8+0], p0);
      p1 = FDOT2(as_h2(ha.y), w[kq*8+1], p1);
      p2 = FDOT2(as_h2(ha.z), w[kq*8+2], p2);
      p3 = FDOT2(as_h2(ha.w), w[kq*8+3], p3);
      p0 = FDOT2(as_h2(hb.x), w[kq*8+4], p0);
      p1 = FDOT2(as_h2(hb.y), w[kq*8+5], p1);
      p2 = FDOT2(as_h2(hb.z), w[kq*8+6], p2);
      p3 = FDOT2(as_h2(hb.w), w[kq*8+7], p3);
    }
    float a = (p0 + p1) + (p2 + p3);
    a += qperm<QP_XOR1>(a);                  // kh-pair reduce -> full dot in both lanes
    // own activation: sigmoid for g in {0,1,3}, tanh via scaled sigmoid for g==2
    float s  = 1.f/(1.f + __expf(-km*a));
    float act = (g == 2) ? (2.f*s - 1.f) : s;
    // all-gate exchange within the 8-lane d-group (act is kh-invariant):
    float A1 = qperm<QP_XOR2>(act);          // lane^2 -> gate g^1
    float A3 = qperm<ROW_HMIRR>(act);        // lane^7 -> gate g^3
    float A2 = qperm<QP_XOR3>(A3);           // (lane^7)^3 = lane^4 -> gate g^2
    // gate_j = u[g^j]; select with 8 cndmasks
    float pl = b0m ? A1  : act;
    float ph = b0m ? A3  : A2;
    float ql = b0m ? act : A1;
    float qh = b0m ? A2  : A3;
    float i_ = b1m ? ph : pl;     // gate 0
    float f_ = b1m ? qh : ql;     // gate 1
    float g_ = b1m ? pl : ph;     // gate 2
    float o_ = b1m ? ql : qh;     // gate 3
    creg = f_*creg + i_*g_;
    float ec = __expf(2.f*creg); float tc = 1.f - 2.f/(ec+1.f);
    hreg = o_*tc;
    if ((tid & 7) == 0){                     // one writer per d
      union{ _Float16 f; unsigned short s; } cv; cv.f = (_Float16)hreg;
      hsh[(t+1) & 1][tid >> 3] = cv.s;
    }
    __syncthreads();
    xc = xa; xa = xb;
  }

  // fused FC: out[b] = sum_d h_d * fcw[d] + fcb
  if ((tid & 7) == 0) red[tid >> 3] = hreg * fcw[tid >> 3];
  __syncthreads();
  #pragma unroll
  for (int s2=64; s2>=1; s2>>=1){
    if (tid < s2) red[tid] += red[tid+s2];
    __syncthreads();
  }
  if (tid == 0) out[b] = red[0] + fcb[0];
}

extern "C" void kernel_launch(void* const* d_in, const int* in_sizes, int n_in,
                              void* d_out, int out_size, void* d_ws, size_t ws_size,
                              hipStream_t stream){
  const float* x   = (const float*)d_in[0];
  const float* Wih = (const float*)d_in[1];
  const float* Whh = (const float*)d_in[2];
  const float* bih = (const float*)d_in[3];
  const float* bhh = (const float*)d_in[4];
  const float* fcw = (const float*)d_in[5];
  const float* fcb = (const float*)d_in[6];
  float* out = (float*)d_out;
  char* ws = (char*)d_ws;

  // ws layout (bytes):
  //   x16  : 0          .. 83,886,080   (131072*320 f16)
  //   W16  : 83,886,080 .. +327,680     (512*320 f16, rows permuted d*4+g)
  //   Whh2 : 84,213,760 .. +131,072     (1024*32 half2, K-split per-thread layout)
  //   bias : 84,344,832 .. +2,048       (512 f32, permuted d*4+g)
  //   xg   : 84,346,880 .. +268,435,456 (131072*512 f32, cols permuted d*4+g)
  unsigned int* x16   = (unsigned int*)(ws);
  unsigned int* W16   = (unsigned int*)(ws + 83886080);
  unsigned int* Whh2w = (unsigned int*)(ws + 84213760);
  float*        bias  = (float*)      (ws + 84344832);
  float*        xg    = (float*)      (ws + 84346880);

  hipLaunchKernelGGL(conv_x,     dim3(81920),  dim3(256), 0, stream, x, x16);
  hipLaunchKernelGGL(conv_small, dim3(450),    dim3(256), 0, stream, Wih, Whh, bih, bhh, W16, Whh2w, bias);
  hipLaunchKernelGGL(gemm16,     dim3(1024,4), dim3(256), 0, stream,
                     (const _Float16*)x16, (const _Float16*)W16, bias, xg);
  hipLaunchKernelGGL(lstm_rec,   dim3(256),    dim3(1024), 0, stream, xg, Whh2w, fcw, fcb, out);
}